// Round 1
// baseline (1825.782 us; speedup 1.0000x reference)
//
#include <hip/hip_runtime.h>

#define BATCH   1024
#define MSIZE   65536
#define KDIM    256
#define CHOOSEK 128
#define BETA    1e-8f
#define ALPHA   0.5f

// -------------------------------------------------------------------------
// Kernel 1: fp32 GEMM  sims = q @ key^T, epilogue -> score = exp(sim-1)*(hist+beta)
// stored as u16 = top 16 bits of the positive float (monotonic sort key).
// Tile: 32 batch x 256 mem per 256-thread WG; thread tile 4x8; K sliced by 32.
// -------------------------------------------------------------------------
__global__ __launch_bounds__(256)
void score_u16_kernel(const float* __restrict__ q,
                      const float* __restrict__ key,
                      const float* __restrict__ hist,
                      unsigned short* __restrict__ s16)
{
    __shared__ float Qs[32 * 36];    // stride 36 floats: keeps 16B align, spreads banks
    __shared__ float Ks[256 * 36];
    const int tid = threadIdx.x;
    const int b0  = blockIdx.x * 32;
    const int m0  = blockIdx.y * 256;
    const int tr  = tid >> 5;        // 0..7  -> batch sub-tile (4 rows each)
    const int tc  = tid & 31;        // 0..31 -> mem rows {tc + 32j}

    float acc[4][8];
#pragma unroll
    for (int r = 0; r < 4; ++r)
#pragma unroll
        for (int c = 0; c < 8; ++c) acc[r][c] = 0.f;

    for (int ks = 0; ks < KDIM; ks += 32) {
        {   // stage Q slice: 32 rows x 32 k  (1 float4/thread)
            int row = tid >> 3, k4 = (tid & 7) * 4;
            float4 v = *reinterpret_cast<const float4*>(
                &q[(size_t)(b0 + row) * KDIM + ks + k4]);
            *reinterpret_cast<float4*>(&Qs[row * 36 + k4]) = v;
        }
#pragma unroll
        for (int i = 0; i < 8; ++i) {   // stage K slice: 256 rows x 32 k
            int l = i * 256 + tid;
            int row = l >> 3, k4 = (l & 7) * 4;
            float4 v = *reinterpret_cast<const float4*>(
                &key[(size_t)(m0 + row) * KDIM + ks + k4]);
            *reinterpret_cast<float4*>(&Ks[row * 36 + k4]) = v;
        }
        __syncthreads();
#pragma unroll
        for (int kb = 0; kb < 8; ++kb) {
            float4 qv[4], kv[8];
#pragma unroll
            for (int r = 0; r < 4; ++r)   // broadcast within 32-lane group (free)
                qv[r] = *reinterpret_cast<const float4*>(&Qs[(tr * 4 + r) * 36 + kb * 4]);
#pragma unroll
            for (int c = 0; c < 8; ++c)
                kv[c] = *reinterpret_cast<const float4*>(&Ks[(tc + 32 * c) * 36 + kb * 4]);
#pragma unroll
            for (int r = 0; r < 4; ++r)
#pragma unroll
                for (int c = 0; c < 8; ++c)
                    acc[r][c] += qv[r].x * kv[c].x + qv[r].y * kv[c].y
                               + qv[r].z * kv[c].z + qv[r].w * kv[c].w;
        }
        __syncthreads();
    }

#pragma unroll
    for (int c = 0; c < 8; ++c) {
        int m = m0 + tc + 32 * c;
        float h = hist[m] + BETA;
#pragma unroll
        for (int r = 0; r < 4; ++r) {
            float sc = expf(acc[r][c] - 1.0f) * h;   // > 0 always
            s16[(size_t)(b0 + tr * 4 + r) * MSIZE + m] =
                (unsigned short)(__float_as_uint(sc) >> 16);
        }
    }
}

// -------------------------------------------------------------------------
// Kernel 2: per batch row — radix-select rank-128 threshold on u16 keys,
// gather candidates (u16 >= T16, a superset of the exact top-128), exact fp32
// rescore, count-based exact top-128 (ties -> lower index, matching lax.top_k),
// then result = sum(j*v)/sum(j) with j = exp(sim-1)*(alpha*hist+beta).
// -------------------------------------------------------------------------
__global__ __launch_bounds__(256)
void select_kernel(const float* __restrict__ q,
                   const float* __restrict__ key,
                   const float* __restrict__ hist,
                   const float* __restrict__ vals,
                   const unsigned short* __restrict__ s16,
                   float* __restrict__ out)
{
    const int b   = blockIdx.x;
    const int tid = threadIdx.x;

    __shared__ float qs[KDIM];
    __shared__ unsigned int hcnt[16 * 257];   // 16 replicated histograms (atomic spread)
    __shared__ int   stot[256];
    __shared__ int   scal[4];                 // 0:H  1:nAboveH  2:T16  3:ncand
    __shared__ int   cidx[2048];
    __shared__ float csc[2048], cjj[2048], cjv[2048];
    __shared__ float wred[8];

    qs[tid] = q[(size_t)b * KDIM + tid];
    for (int i = tid; i < 16 * 257; i += 256) hcnt[i] = 0u;
    __syncthreads();

    const uint4* rowp = reinterpret_cast<const uint4*>(s16 + (size_t)b * MSIZE);
    const int rep = (tid & 15) * 257;

    // ---- pass 1: histogram of high byte ----
    for (int i = 0; i < 32; ++i) {
        uint4 v = rowp[i * 256 + tid];
        unsigned int w[4] = {v.x, v.y, v.z, v.w};
#pragma unroll
        for (int k = 0; k < 4; ++k) {
            atomicAdd(&hcnt[rep + ((w[k] >> 8) & 0xffu)], 1u);   // low u16's high byte
            atomicAdd(&hcnt[rep + (w[k] >> 24)], 1u);            // high u16's high byte
        }
    }
    __syncthreads();
    { unsigned int t = 0;
#pragma unroll
      for (int k = 0; k < 16; ++k) t += hcnt[k * 257 + tid];
      stot[tid] = (int)t; }
    __syncthreads();
    for (int off = 1; off < 256; off <<= 1) {   // suffix sum (descending cumulative)
        int v = stot[tid] + ((tid + off < 256) ? stot[tid + off] : 0);
        __syncthreads(); stot[tid] = v; __syncthreads();
    }
    { int sH = stot[tid], sN = (tid < 255) ? stot[tid + 1] : 0;
      if (sH >= CHOOSEK && sN < CHOOSEK) { scal[0] = tid; scal[1] = sN; } }
    __syncthreads();
    const int H = scal[0], nAbove = scal[1];

    for (int i = tid; i < 16 * 257; i += 256) hcnt[i] = 0u;
    __syncthreads();

    // ---- pass 2: low-byte histogram among entries with high byte == H ----
    for (int i = 0; i < 32; ++i) {
        uint4 v = rowp[i * 256 + tid];
        unsigned int w[4] = {v.x, v.y, v.z, v.w};
#pragma unroll
        for (int k = 0; k < 4; ++k) {
            unsigned int u0 = w[k] & 0xffffu, u1 = w[k] >> 16;
            if ((int)(u0 >> 8) == H) atomicAdd(&hcnt[rep + (u0 & 0xffu)], 1u);
            if ((int)(u1 >> 8) == H) atomicAdd(&hcnt[rep + (u1 & 0xffu)], 1u);
        }
    }
    __syncthreads();
    { unsigned int t = 0;
#pragma unroll
      for (int k = 0; k < 16; ++k) t += hcnt[k * 257 + tid];
      stot[tid] = (int)t; }
    __syncthreads();
    for (int off = 1; off < 256; off <<= 1) {
        int v = stot[tid] + ((tid + off < 256) ? stot[tid + off] : 0);
        __syncthreads(); stot[tid] = v; __syncthreads();
    }
    { int sH2 = nAbove + stot[tid];
      int sN2 = nAbove + ((tid < 255) ? stot[tid + 1] : 0);
      if (sH2 >= CHOOSEK && sN2 < CHOOSEK) scal[2] = (H << 8) | tid;
      if (tid == 0) scal[3] = 0; }
    __syncthreads();
    const unsigned int T16 = (unsigned int)scal[2];

    // ---- pass 3: collect candidate indices (u16 >= T16) ----
    for (int i = 0; i < 32; ++i) {
        uint4 v = rowp[i * 256 + tid];
        int base = (i * 256 + tid) * 8;
        unsigned int w[4] = {v.x, v.y, v.z, v.w};
#pragma unroll
        for (int k = 0; k < 4; ++k) {
            unsigned int u0 = w[k] & 0xffffu, u1 = w[k] >> 16;
            if (u0 >= T16) { int p = atomicAdd(&scal[3], 1); if (p < 2048) cidx[p] = base + 2 * k; }
            if (u1 >= T16) { int p = atomicAdd(&scal[3], 1); if (p < 2048) cidx[p] = base + 2 * k + 1; }
        }
    }
    __syncthreads();
    const int ncand = min(scal[3], 2048);

    // ---- exact fp32 rescore of candidates (one dot per wave-iteration) ----
    const int wave = tid >> 6, lane = tid & 63;
    for (int i = wave; i < ncand; i += 4) {
        const int idx = cidx[i];
        float4 kk = *reinterpret_cast<const float4*>(&key[(size_t)idx * KDIM + lane * 4]);
        float4 qq = *reinterpret_cast<const float4*>(&qs[lane * 4]);
        float p = kk.x * qq.x + kk.y * qq.y + kk.z * qq.z + kk.w * qq.w;
#pragma unroll
        for (int off = 32; off > 0; off >>= 1) p += __shfl_xor(p, off, 64);
        if (lane == 0) {
            float e = expf(p - 1.0f);
            float h = hist[idx];
            csc[i] = e * (h + BETA);              // selection score
            float j = e * (ALPHA * h + BETA);     // joint
            cjj[i] = j;
            cjv[i] = j * vals[idx];
        }
    }
    __syncthreads();

    // ---- exact top-128 among candidates (count-based; ties -> lower index) ----
    float pn = 0.f, pd = 0.f;
    for (int i = tid; i < ncand; i += 256) {
        float si = csc[i]; int ii = cidx[i]; int rank = 0;
        for (int t = 0; t < ncand; ++t) {
            float st = csc[t];                    // same address across lanes: broadcast
            rank += (st > si || (st == si && cidx[t] < ii)) ? 1 : 0;
        }
        if (rank < CHOOSEK) { pn += cjv[i]; pd += cjj[i]; }
    }
#pragma unroll
    for (int off = 32; off > 0; off >>= 1) {
        pn += __shfl_xor(pn, off, 64);
        pd += __shfl_xor(pd, off, 64);
    }
    if (lane == 0) { wred[wave] = pn; wred[4 + wave] = pd; }
    __syncthreads();
    if (tid == 0) {
        float n = wred[0] + wred[1] + wred[2] + wred[3];
        float d = wred[4] + wred[5] + wred[6] + wred[7];
        out[b] = n / d;
    }
}

// -------------------------------------------------------------------------
extern "C" void kernel_launch(void* const* d_in, const int* in_sizes, int n_in,
                              void* d_out, int out_size, void* d_ws, size_t ws_size,
                              hipStream_t stream)
{
    (void)in_sizes; (void)n_in; (void)out_size; (void)ws_size;
    const float* q    = (const float*)d_in[0];
    const float* key  = (const float*)d_in[1];
    const float* hist = (const float*)d_in[2];
    const float* vals = (const float*)d_in[3];
    float* out = (float*)d_out;
    unsigned short* s16 = (unsigned short*)d_ws;   // needs 1024*65536*2 = 128 MiB

    dim3 g1(BATCH / 32, MSIZE / 256);
    score_u16_kernel<<<g1, 256, 0, stream>>>(q, key, hist, s16);
    select_kernel<<<BATCH, 256, 0, stream>>>(q, key, hist, vals, s16, out);
}

// Round 2
// 366.362 us; speedup vs baseline: 4.9835x; 4.9835x over previous
//
#include <hip/hip_runtime.h>

#define BATCH   1024
#define MSIZE   65536
#define KDIM    256
#define CHOOSEK 128
#define SELK    160      // radix-select margin: superset depth > CHOOSEK to absorb bf16 screening error
#define BETA    1e-8f
#define ALPHA   0.5f

typedef short bf16x8 __attribute__((ext_vector_type(8)));
typedef float f32x4  __attribute__((ext_vector_type(4)));

#define LDA 40   // bf16/row: 32 + 8 pad; rows 80 B (16B-aligned), worst 2-way bank alias (free)

__device__ inline unsigned int pack2bf(float a, float b) {   // RNE fp32->bf16 pair
    unsigned int ua = __float_as_uint(a);
    unsigned int ub = __float_as_uint(b);
    ua += 0x7fffu + ((ua >> 16) & 1u);
    ub += 0x7fffu + ((ub >> 16) & 1u);
    return (ua >> 16) | (ub & 0xffff0000u);
}

// -------------------------------------------------------------------------
// Kernel 1: bf16-MFMA screening GEMM. 128(batch) x 128(mem) per 256-thread WG,
// 4 waves each own a 64x64 subtile = 4x4 grid of 16x16x32 MFMAs, BK=32.
// Epilogue: score = exp(sim-1)*(hist+beta) -> u16 sort key (top 16 bits).
// -------------------------------------------------------------------------
__global__ __launch_bounds__(256)
void score_u16_kernel(const float* __restrict__ q,
                      const float* __restrict__ key,
                      const float* __restrict__ hist,
                      unsigned short* __restrict__ s16)
{
    __shared__ unsigned short As[128 * LDA];
    __shared__ unsigned short Bs[128 * LDA];
    const int tid  = threadIdx.x;
    const int b0   = blockIdx.x * 128;   // batch tile
    const int n0   = blockIdx.y * 128;   // memory tile
    const int lane = tid & 63;
    const int wave = tid >> 6;
    const int wm   = (wave >> 1) * 64;
    const int wn   = (wave & 1) * 64;
    const int l15  = lane & 15;
    const int l4   = lane >> 4;

    const int srow = tid >> 1;           // staging: 2 threads/row, 16 floats each
    const int sseg = (tid & 1) * 16;

    f32x4 acc[4][4] = {};

    const float* gA = q   + (size_t)(b0 + srow) * KDIM + sseg;
    const float* gB = key + (size_t)(n0 + srow) * KDIM + sseg;
    uint4* wA = (uint4*)((char*)As + srow * (LDA * 2) + sseg * 2);
    uint4* wB = (uint4*)((char*)Bs + srow * (LDA * 2) + sseg * 2);

    for (int ks = 0; ks < KDIM; ks += 32) {
        float4 a0 = *(const float4*)(gA + ks);
        float4 a1 = *(const float4*)(gA + ks + 4);
        float4 a2 = *(const float4*)(gA + ks + 8);
        float4 a3 = *(const float4*)(gA + ks + 12);
        float4 c0 = *(const float4*)(gB + ks);
        float4 c1 = *(const float4*)(gB + ks + 4);
        float4 c2 = *(const float4*)(gB + ks + 8);
        float4 c3 = *(const float4*)(gB + ks + 12);

        uint4 pa0 = make_uint4(pack2bf(a0.x, a0.y), pack2bf(a0.z, a0.w),
                               pack2bf(a1.x, a1.y), pack2bf(a1.z, a1.w));
        uint4 pa1 = make_uint4(pack2bf(a2.x, a2.y), pack2bf(a2.z, a2.w),
                               pack2bf(a3.x, a3.y), pack2bf(a3.z, a3.w));
        uint4 pb0 = make_uint4(pack2bf(c0.x, c0.y), pack2bf(c0.z, c0.w),
                               pack2bf(c1.x, c1.y), pack2bf(c1.z, c1.w));
        uint4 pb1 = make_uint4(pack2bf(c2.x, c2.y), pack2bf(c2.z, c2.w),
                               pack2bf(c3.x, c3.y), pack2bf(c3.z, c3.w));
        wA[0] = pa0; wA[1] = pa1;
        wB[0] = pb0; wB[1] = pb1;
        __syncthreads();

        bf16x8 af[4], bfr[4];
#pragma unroll
        for (int i = 0; i < 4; ++i)
            af[i] = *(const bf16x8*)((const char*)As + (wm + i * 16 + l15) * (LDA * 2) + l4 * 16);
#pragma unroll
        for (int j = 0; j < 4; ++j)
            bfr[j] = *(const bf16x8*)((const char*)Bs + (wn + j * 16 + l15) * (LDA * 2) + l4 * 16);
#pragma unroll
        for (int i = 0; i < 4; ++i)
#pragma unroll
            for (int j = 0; j < 4; ++j)
                acc[i][j] = __builtin_amdgcn_mfma_f32_16x16x32_bf16(af[i], bfr[j], acc[i][j], 0, 0, 0);
        __syncthreads();
    }

    // epilogue: C/D layout col = lane&15, row = (lane>>4)*4 + reg
    float hj[4];
#pragma unroll
    for (int j = 0; j < 4; ++j)
        hj[j] = hist[n0 + wn + j * 16 + l15] + BETA;
#pragma unroll
    for (int i = 0; i < 4; ++i) {
        int r0 = b0 + wm + i * 16 + l4 * 4;
#pragma unroll
        for (int j = 0; j < 4; ++j) {
            int n = n0 + wn + j * 16 + l15;
            unsigned short* outp = s16 + (size_t)r0 * MSIZE + n;
#pragma unroll
            for (int reg = 0; reg < 4; ++reg) {
                float sc = __expf(acc[i][j][reg] - 1.0f) * hj[j];
                outp[(size_t)reg * MSIZE] = (unsigned short)(__float_as_uint(sc) >> 16);
            }
        }
    }
}

// -------------------------------------------------------------------------
// Kernel 2: per batch row — radix-select rank-SELK threshold on u16 keys,
// gather candidates (u16 >= T16, superset of exact top-128), exact fp32
// rescore, count-based exact top-128 (ties -> lower index, matches lax.top_k),
// then result = sum(j*v)/sum(j), j = exp(sim-1)*(alpha*hist+beta).
// -------------------------------------------------------------------------
__global__ __launch_bounds__(256)
void select_kernel(const float* __restrict__ q,
                   const float* __restrict__ key,
                   const float* __restrict__ hist,
                   const float* __restrict__ vals,
                   const unsigned short* __restrict__ s16,
                   float* __restrict__ out)
{
    const int b   = blockIdx.x;
    const int tid = threadIdx.x;

    __shared__ float qs[KDIM];
    __shared__ unsigned int hcnt[16 * 257];   // 16 replicated histograms (atomic spread)
    __shared__ int   stot[256];
    __shared__ int   scal[4];                 // 0:H  1:nAboveH  2:T16  3:ncand
    __shared__ int   cidx[2048];
    __shared__ float csc[2048], cjj[2048], cjv[2048];
    __shared__ float wred[8];

    qs[tid] = q[(size_t)b * KDIM + tid];
    for (int i = tid; i < 16 * 257; i += 256) hcnt[i] = 0u;
    __syncthreads();

    const uint4* rowp = reinterpret_cast<const uint4*>(s16 + (size_t)b * MSIZE);
    const int rep = (tid & 15) * 257;

    // ---- pass 1: histogram of high byte ----
    for (int i = 0; i < 32; ++i) {
        uint4 v = rowp[i * 256 + tid];
        unsigned int w[4] = {v.x, v.y, v.z, v.w};
#pragma unroll
        for (int k = 0; k < 4; ++k) {
            atomicAdd(&hcnt[rep + ((w[k] >> 8) & 0xffu)], 1u);
            atomicAdd(&hcnt[rep + (w[k] >> 24)], 1u);
        }
    }
    __syncthreads();
    { unsigned int t = 0;
#pragma unroll
      for (int k = 0; k < 16; ++k) t += hcnt[k * 257 + tid];
      stot[tid] = (int)t; }
    __syncthreads();
    for (int off = 1; off < 256; off <<= 1) {   // suffix sum
        int v = stot[tid] + ((tid + off < 256) ? stot[tid + off] : 0);
        __syncthreads(); stot[tid] = v; __syncthreads();
    }
    { int sH = stot[tid], sN = (tid < 255) ? stot[tid + 1] : 0;
      if (sH >= SELK && sN < SELK) { scal[0] = tid; scal[1] = sN; } }
    __syncthreads();
    const int H = scal[0], nAbove = scal[1];

    for (int i = tid; i < 16 * 257; i += 256) hcnt[i] = 0u;
    __syncthreads();

    // ---- pass 2: low-byte histogram among entries with high byte == H ----
    for (int i = 0; i < 32; ++i) {
        uint4 v = rowp[i * 256 + tid];
        unsigned int w[4] = {v.x, v.y, v.z, v.w};
#pragma unroll
        for (int k = 0; k < 4; ++k) {
            unsigned int u0 = w[k] & 0xffffu, u1 = w[k] >> 16;
            if ((int)(u0 >> 8) == H) atomicAdd(&hcnt[rep + (u0 & 0xffu)], 1u);
            if ((int)(u1 >> 8) == H) atomicAdd(&hcnt[rep + (u1 & 0xffu)], 1u);
        }
    }
    __syncthreads();
    { unsigned int t = 0;
#pragma unroll
      for (int k = 0; k < 16; ++k) t += hcnt[k * 257 + tid];
      stot[tid] = (int)t; }
    __syncthreads();
    for (int off = 1; off < 256; off <<= 1) {
        int v = stot[tid] + ((tid + off < 256) ? stot[tid + off] : 0);
        __syncthreads(); stot[tid] = v; __syncthreads();
    }
    { int sH2 = nAbove + stot[tid];
      int sN2 = nAbove + ((tid < 255) ? stot[tid + 1] : 0);
      if (sH2 >= SELK && sN2 < SELK) scal[2] = (H << 8) | tid;
      if (tid == 0) scal[3] = 0; }
    __syncthreads();
    const unsigned int T16 = (unsigned int)scal[2];

    // ---- pass 3: collect candidate indices (u16 >= T16) ----
    for (int i = 0; i < 32; ++i) {
        uint4 v = rowp[i * 256 + tid];
        int base = (i * 256 + tid) * 8;
        unsigned int w[4] = {v.x, v.y, v.z, v.w};
#pragma unroll
        for (int k = 0; k < 4; ++k) {
            unsigned int u0 = w[k] & 0xffffu, u1 = w[k] >> 16;
            if (u0 >= T16) { int p = atomicAdd(&scal[3], 1); if (p < 2048) cidx[p] = base + 2 * k; }
            if (u1 >= T16) { int p = atomicAdd(&scal[3], 1); if (p < 2048) cidx[p] = base + 2 * k + 1; }
        }
    }
    __syncthreads();
    const int ncand = min(scal[3], 2048);

    // ---- exact fp32 rescore of candidates ----
    const int wave = tid >> 6, lane = tid & 63;
    for (int i = wave; i < ncand; i += 4) {
        const int idx = cidx[i];
        float4 kk = *reinterpret_cast<const float4*>(&key[(size_t)idx * KDIM + lane * 4]);
        float4 qq = *reinterpret_cast<const float4*>(&qs[lane * 4]);
        float p = kk.x * qq.x + kk.y * qq.y + kk.z * qq.z + kk.w * qq.w;
#pragma unroll
        for (int off = 32; off > 0; off >>= 1) p += __shfl_xor(p, off, 64);
        if (lane == 0) {
            float e = expf(p - 1.0f);
            float h = hist[idx];
            csc[i] = e * (h + BETA);
            float j = e * (ALPHA * h + BETA);
            cjj[i] = j;
            cjv[i] = j * vals[idx];
        }
    }
    __syncthreads();

    // ---- exact top-128 among candidates (count-based; ties -> lower index) ----
    float pn = 0.f, pd = 0.f;
    for (int i = tid; i < ncand; i += 256) {
        float si = csc[i]; int ii = cidx[i]; int rank = 0;
        for (int t = 0; t < ncand; ++t) {
            float st = csc[t];
            rank += (st > si || (st == si && cidx[t] < ii)) ? 1 : 0;
        }
        if (rank < CHOOSEK) { pn += cjv[i]; pd += cjj[i]; }
    }
#pragma unroll
    for (int off = 32; off > 0; off >>= 1) {
        pn += __shfl_xor(pn, off, 64);
        pd += __shfl_xor(pd, off, 64);
    }
    if (lane == 0) { wred[wave] = pn; wred[4 + wave] = pd; }
    __syncthreads();
    if (tid == 0) {
        float n = wred[0] + wred[1] + wred[2] + wred[3];
        float d = wred[4] + wred[5] + wred[6] + wred[7];
        out[b] = n / d;
    }
}

// -------------------------------------------------------------------------
extern "C" void kernel_launch(void* const* d_in, const int* in_sizes, int n_in,
                              void* d_out, int out_size, void* d_ws, size_t ws_size,
                              hipStream_t stream)
{
    (void)in_sizes; (void)n_in; (void)out_size; (void)ws_size;
    const float* q    = (const float*)d_in[0];
    const float* key  = (const float*)d_in[1];
    const float* hist = (const float*)d_in[2];
    const float* vals = (const float*)d_in[3];
    float* out = (float*)d_out;
    unsigned short* s16 = (unsigned short*)d_ws;   // 1024*65536*2 = 128 MiB

    dim3 g1(BATCH / 128, MSIZE / 128);
    score_u16_kernel<<<g1, 256, 0, stream>>>(q, key, hist, s16);
    select_kernel<<<BATCH, 256, 0, stream>>>(q, key, hist, vals, s16, out);
}